// Round 3
// baseline (830.519 us; speedup 1.0000x reference)
//
#include <hip/hip_runtime.h>
#include <math.h>

#define NA 16384
#define NE 262144

// workspace layout in floats
#define SI_OFF   0                         // [NA][3]
#define SB_OFF   (NA*3)                    // [3][NA][96]
#define NM_OFF   (SB_OFF + 3*NA*96)        // [NA][32][16]  (13 used, pad 16)
#define RWT_OFF  (NM_OFF + NA*512)         // [3][96][8]  rbf_w transposed

__global__ __launch_bounds__(256) void repack_rw_k(const float* __restrict__ rbf_w,
                                                   float* __restrict__ ws) {
    int t = blockIdx.x * 256 + threadIdx.x;       // over 3*96*8 = 2304
    if (t >= 2304) return;
    int k = t & 7;
    int c = (t >> 3) % 96;
    int w = t / 768;
    ws[RWT_OFF + t] = rbf_w[w * 768 + k * 96 + c];
}

__global__ __launch_bounds__(256) void atom_prep_k(
    const float* __restrict__ node0, const float* __restrict__ node1,
    const float* __restrict__ node2, const float* __restrict__ spin,
    const float* __restrict__ srbf_w, const float* __restrict__ srbf_b,
    const float* __restrict__ U_w, float* __restrict__ ws)
{
    const int wave = threadIdx.x >> 6;
    const int lane = threadIdx.x & 63;
    const int a = blockIdx.x * 4 + wave;
    if (a >= NA) return;

    float sx = spin[a*3+0], sy = spin[a*3+1], sz = spin[a*3+2];
    float mi = sqrtf(sx*sx + sy*sy + sz*sz + 1e-12f);
    float inv = 1.0f / mi;
    if (lane < 3) ws[SI_OFF + a*3 + lane] = spin[a*3 + lane] * inv;

    float srbf[8];
    #pragma unroll
    for (int k = 0; k < 8; ++k) {
        float d = mi - (float)k * (3.0f / 7.0f);
        srbf[k] = expf(-4.0f * d * d);
    }

    #pragma unroll
    for (int w = 0; w < 3; ++w) {
        #pragma unroll
        for (int rep = 0; rep < 2; ++rep) {
            int c = rep * 64 + lane;
            if (c < 96) {
                float acc = srbf_b[w*96 + c];
                #pragma unroll
                for (int k = 0; k < 8; ++k)
                    acc = fmaf(srbf[k], srbf_w[w*768 + k*96 + c], acc);
                ws[SB_OFF + ((size_t)w*NA + a)*96 + c] = acc;
            }
        }
    }

    const int o = lane & 31;
    const int h = lane >> 5;
    float acc[13];
    #pragma unroll
    for (int sp = 0; sp < 13; ++sp) acc[sp] = 0.0f;

    for (int cc = 0; cc < 16; ++cc) {
        int c = h * 16 + cc;
        float f0 = node0[a*32 + c];
        float u0 = U_w[0*1024 + c*32 + o];
        float u1 = U_w[1*1024 + c*32 + o];
        float u2 = U_w[2*1024 + c*32 + o];
        acc[0] = fmaf(f0, u0, acc[0]);
        #pragma unroll
        for (int jj = 0; jj < 3; ++jj)
            acc[1+jj] = fmaf(node1[a*96 + c*3 + jj], u1, acc[1+jj]);
        #pragma unroll
        for (int ij = 0; ij < 9; ++ij)
            acc[4+ij] = fmaf(node2[a*288 + c*9 + ij], u2, acc[4+ij]);
    }
    #pragma unroll
    for (int sp = 0; sp < 13; ++sp)
        acc[sp] += __shfl_xor(acc[sp], 32);

    if (h == 0) {
        float* p = ws + NM_OFF + (size_t)a*512 + o*16;
        *(float4*)(p + 0)  = make_float4(acc[0], acc[1], acc[2], acc[3]);
        *(float4*)(p + 4)  = make_float4(acc[4], acc[5], acc[6], acc[7]);
        *(float4*)(p + 8)  = make_float4(acc[8], acc[9], acc[10], acc[11]);
        *(float4*)(p + 12) = make_float4(acc[12], 0.f, 0.f, 0.f);
    }
}

// Fully fused edge kernel: natural e-order (dense output writes), 8 threads
// per edge. Thread q accumulates s[w][4q..4q+3] in registers; the per-edge
// g[96] coefficients are shared through a small padded LDS buffer. No sort,
// no scratch, no second pass.
__global__ __launch_bounds__(256) void edge_fused_k(
    const float* __restrict__ coord, const int* __restrict__ idx_i,
    const int* __restrict__ idx_j, const float* __restrict__ rbf_b,
    const float* __restrict__ V_w, const float* __restrict__ ws,
    float* __restrict__ out)
{
    __shared__ float gbuf[32 * 100];           // [group][96 + 4 pad]
    const int tid = threadIdx.x;
    const int grp = tid >> 3;
    const int q   = tid & 7;
    const int e   = blockIdx.x * 32 + grp;     // natural order
    const int i = idx_i[e];
    const int j = idx_j[e];

    float rx = coord[j*3+0] - coord[i*3+0];
    float ry = coord[j*3+1] - coord[i*3+1];
    float rz = coord[j*3+2] - coord[i*3+2];
    float d2 = rx*rx + ry*ry + rz*rz + 1e-12f;
    float dij = sqrtf(d2);
    float invd = 1.0f / dij;
    float ux = rx*invd, uy = ry*invd, uz = rz*invd;

    float tt = fminf(dij * 0.2f, 1.0f);
    float fc = 0.5f * (cosf(3.14159265358979323846f * tt) + 1.0f);
    float rbf[8];
    #pragma unroll
    for (int k = 0; k < 8; ++k) {
        float d = dij - (float)k * (5.0f / 7.0f);
        rbf[k] = expf(-4.0f * d * d) * fc;
    }

    const float* si = ws + SI_OFF;
    float sij = si[i*3+0]*si[j*3+0] + si[i*3+1]*si[j*3+1] + si[i*3+2]*si[j*3+2];
    float cheb1 = sij;
    float cheb2 = 2.0f * sij * sij - 1.0f;

    float sacc[3][4];
    #pragma unroll
    for (int w = 0; w < 3; ++w)
        #pragma unroll
        for (int r = 0; r < 4; ++r) sacc[w][r] = 0.0f;

    #pragma unroll
    for (int w = 0; w < 3; ++w) {
        const float* sbi = ws + SB_OFF + ((size_t)w*NA + i)*96 + q*12;
        const float* sbj = ws + SB_OFF + ((size_t)w*NA + j)*96 + q*12;
        const float* rwt = ws + RWT_OFF + w*768;   // [96][8]
        const float* rbb = rbf_b + w*96 + q*12;

        float4 bi0 = *(const float4*)(sbi + 0);
        float4 bi1 = *(const float4*)(sbi + 4);
        float4 bi2 = *(const float4*)(sbi + 8);
        float4 bj0 = *(const float4*)(sbj + 0);
        float4 bj1 = *(const float4*)(sbj + 4);
        float4 bj2 = *(const float4*)(sbj + 8);
        float4 rb0 = *(const float4*)(rbb + 0);
        float4 rb1 = *(const float4*)(rbb + 4);
        float4 rb2 = *(const float4*)(rbb + 8);
        float bi_[12] = {bi0.x,bi0.y,bi0.z,bi0.w, bi1.x,bi1.y,bi1.z,bi1.w,
                         bi2.x,bi2.y,bi2.z,bi2.w};
        float bj_[12] = {bj0.x,bj0.y,bj0.z,bj0.w, bj1.x,bj1.y,bj1.z,bj1.w,
                         bj2.x,bj2.y,bj2.z,bj2.w};
        float rb_[12] = {rb0.x,rb0.y,rb0.z,rb0.w, rb1.x,rb1.y,rb1.z,rb1.w,
                         rb2.x,rb2.y,rb2.z,rb2.w};

        float gv[12];
        #pragma unroll
        for (int kk = 0; kk < 12; ++kk) {
            int c = q*12 + kk;
            float4 ra = *(const float4*)(rwt + c*8);
            float4 rbx = *(const float4*)(rwt + c*8 + 4);
            float rm = rb_[kk];
            rm = fmaf(rbf[0], ra.x, rm);
            rm = fmaf(rbf[1], ra.y, rm);
            rm = fmaf(rbf[2], ra.z, rm);
            rm = fmaf(rbf[3], ra.w, rm);
            rm = fmaf(rbf[4], rbx.x, rm);
            rm = fmaf(rbf[5], rbx.y, rm);
            rm = fmaf(rbf[6], rbx.z, rm);
            rm = fmaf(rbf[7], rbx.w, rm);
            int tb = c >> 5;
            float chb = (tb == 0) ? 1.0f : ((tb == 1) ? cheb1 : cheb2);
            gv[kk] = rm * (bi_[kk] * bj_[kk]) * chb;
        }
        float* gb = gbuf + grp*100 + q*12;
        *(float4*)(gb + 0) = make_float4(gv[0], gv[1], gv[2],  gv[3]);
        *(float4*)(gb + 4) = make_float4(gv[4], gv[5], gv[6],  gv[7]);
        *(float4*)(gb + 8) = make_float4(gv[8], gv[9], gv[10], gv[11]);
        __syncthreads();

        const float* vw = V_w + w*3072 + q*4;      // [96][32], o-slice
        const float* gg = gbuf + grp*100;
        #pragma unroll 6
        for (int c4 = 0; c4 < 24; ++c4) {
            float4 g4 = *(const float4*)(gg + c4*4);
            float gcs[4] = {g4.x, g4.y, g4.z, g4.w};
            #pragma unroll
            for (int u4 = 0; u4 < 4; ++u4) {
                int c = c4*4 + u4;
                float gc = gcs[u4];
                float4 vv = *(const float4*)(vw + c*32);
                sacc[w][0] = fmaf(vv.x, gc, sacc[w][0]);
                sacc[w][1] = fmaf(vv.y, gc, sacc[w][1]);
                sacc[w][2] = fmaf(vv.z, gc, sacc[w][2]);
                sacc[w][3] = fmaf(vv.w, gc, sacc[w][3]);
            }
        }
        __syncthreads();
    }

    // epilogue: thread q owns o = 4q..4q+3; s and u already in registers
    const float* nmj = ws + NM_OFF + (size_t)j*512 + q*64;

    float r0[4], r1[12], r2[36];
    #pragma unroll
    for (int oo = 0; oo < 4; ++oo) {
        const float* nmo = nmj + oo*16;
        float4 va  = *(const float4*)(nmo + 0);
        float4 vb  = *(const float4*)(nmo + 4);
        float4 vc4 = *(const float4*)(nmo + 8);
        float nd   = nmo[12];
        float n0 = va.x, n1x = va.y, n1y = va.z, n1z = va.w;
        float t00 = vb.x, t01 = vb.y, t02 = vb.z, t10 = vb.w;
        float t11 = vc4.x, t12 = vc4.y, t20 = vc4.z, t21 = vc4.w, t22 = nd;
        float s0 = sacc[0][oo], s1 = sacc[1][oo], s2 = sacc[2][oo];

        float d1 = n1x*ux + n1y*uy + n1z*uz;
        float m0 = t00*ux + t01*uy + t02*uz;
        float m1 = t10*ux + t11*uy + t12*uz;
        float m2 = t20*ux + t21*uy + t22*uz;
        float qq = m0*ux + m1*uy + m2*uz;

        r0[oo] = n0*s0 + d1*s1 + qq*s2;

        float w1 = n0*s1 + s2*d1;
        r1[oo*3+0] = w1*ux + n1x*s0 + s1*m0;
        r1[oo*3+1] = w1*uy + n1y*s0 + s1*m1;
        r1[oo*3+2] = w1*uz + n1z*s0 + s1*m2;

        float n0s2 = n0*s2;
        float a0 = ux*n0s2 + s1*n1x + s2*m0;
        float a1 = uy*n0s2 + s1*n1y + s2*m1;
        float a2 = uz*n0s2 + s1*n1z + s2*m2;
        r2[oo*9+0] = a0*ux + s0*t00;
        r2[oo*9+1] = a0*uy + s0*t01;
        r2[oo*9+2] = a0*uz + s0*t02;
        r2[oo*9+3] = a1*ux + s0*t10;
        r2[oo*9+4] = a1*uy + s0*t11;
        r2[oo*9+5] = a1*uz + s0*t12;
        r2[oo*9+6] = a2*ux + s0*t20;
        r2[oo*9+7] = a2*uy + s0*t21;
        r2[oo*9+8] = a2*uz + s0*t22;
    }

    *(float4*)(out + (size_t)e*32 + q*4) =
        make_float4(r0[0], r0[1], r0[2], r0[3]);

    float* p1 = out + (size_t)NE*32 + (size_t)e*96 + q*12;
    #pragma unroll
    for (int k = 0; k < 3; ++k)
        *(float4*)(p1 + k*4) =
            make_float4(r1[k*4+0], r1[k*4+1], r1[k*4+2], r1[k*4+3]);

    float* p2 = out + (size_t)NE*128 + (size_t)e*288 + q*36;
    #pragma unroll
    for (int k = 0; k < 9; ++k)
        *(float4*)(p2 + k*4) =
            make_float4(r2[k*4+0], r2[k*4+1], r2[k*4+2], r2[k*4+3]);
}

extern "C" void kernel_launch(void* const* d_in, const int* in_sizes, int n_in,
                              void* d_out, int out_size, void* d_ws, size_t ws_size,
                              hipStream_t stream) {
    const float* node0  = (const float*)d_in[0];
    const float* node1  = (const float*)d_in[1];
    const float* node2  = (const float*)d_in[2];
    const float* coord  = (const float*)d_in[3];
    const float* spin   = (const float*)d_in[4];
    const int*   idx_i  = (const int*)d_in[5];
    const int*   idx_j  = (const int*)d_in[6];
    const float* rbf_w  = (const float*)d_in[7];
    const float* rbf_b  = (const float*)d_in[8];
    const float* srbf_w = (const float*)d_in[9];
    const float* srbf_b = (const float*)d_in[10];
    const float* U_w    = (const float*)d_in[11];
    const float* V_w    = (const float*)d_in[12];
    float* out = (float*)d_out;
    float* ws  = (float*)d_ws;

    repack_rw_k<<<(2304 + 255) / 256, 256, 0, stream>>>(rbf_w, ws);
    atom_prep_k<<<NA / 4, 256, 0, stream>>>(node0, node1, node2, spin,
                                            srbf_w, srbf_b, U_w, ws);
    edge_fused_k<<<NE / 32, 256, 0, stream>>>(coord, idx_i, idx_j, rbf_b,
                                              V_w, ws, out);
}

// Round 4
// 826.887 us; speedup vs baseline: 1.0044x; 1.0044x over previous
//
#include <hip/hip_runtime.h>
#include <math.h>

#define NA 16384
#define NE 262144

// workspace layout in floats
#define SI_OFF   0                         // [NA][3]
#define SB_OFF   (NA*3)                    // [3][NA][96]
#define NM_OFF   (SB_OFF + 3*NA*96)        // [NA][32][16]  (13 used, pad 16)
#define RWT_OFF  (NM_OFF + NA*512)         // [3][96][8]  rbf_w transposed

__global__ __launch_bounds__(256) void repack_rw_k(const float* __restrict__ rbf_w,
                                                   float* __restrict__ ws) {
    int t = blockIdx.x * 256 + threadIdx.x;       // over 3*96*8 = 2304
    if (t >= 2304) return;
    int k = t & 7;
    int c = (t >> 3) % 96;
    int w = t / 768;
    ws[RWT_OFF + t] = rbf_w[w * 768 + k * 96 + c];
}

__global__ __launch_bounds__(256) void atom_prep_k(
    const float* __restrict__ node0, const float* __restrict__ node1,
    const float* __restrict__ node2, const float* __restrict__ spin,
    const float* __restrict__ srbf_w, const float* __restrict__ srbf_b,
    const float* __restrict__ U_w, float* __restrict__ ws)
{
    const int wave = threadIdx.x >> 6;
    const int lane = threadIdx.x & 63;
    const int a = blockIdx.x * 4 + wave;
    if (a >= NA) return;

    float sx = spin[a*3+0], sy = spin[a*3+1], sz = spin[a*3+2];
    float mi = sqrtf(sx*sx + sy*sy + sz*sz + 1e-12f);
    float inv = 1.0f / mi;
    if (lane < 3) ws[SI_OFF + a*3 + lane] = spin[a*3 + lane] * inv;

    float srbf[8];
    #pragma unroll
    for (int k = 0; k < 8; ++k) {
        float d = mi - (float)k * (3.0f / 7.0f);
        srbf[k] = expf(-4.0f * d * d);
    }

    #pragma unroll
    for (int w = 0; w < 3; ++w) {
        #pragma unroll
        for (int rep = 0; rep < 2; ++rep) {
            int c = rep * 64 + lane;
            if (c < 96) {
                float acc = srbf_b[w*96 + c];
                #pragma unroll
                for (int k = 0; k < 8; ++k)
                    acc = fmaf(srbf[k], srbf_w[w*768 + k*96 + c], acc);
                ws[SB_OFF + ((size_t)w*NA + a)*96 + c] = acc;
            }
        }
    }

    const int o = lane & 31;
    const int h = lane >> 5;
    float acc[13];
    #pragma unroll
    for (int sp = 0; sp < 13; ++sp) acc[sp] = 0.0f;

    for (int cc = 0; cc < 16; ++cc) {
        int c = h * 16 + cc;
        float f0 = node0[a*32 + c];
        float u0 = U_w[0*1024 + c*32 + o];
        float u1 = U_w[1*1024 + c*32 + o];
        float u2 = U_w[2*1024 + c*32 + o];
        acc[0] = fmaf(f0, u0, acc[0]);
        #pragma unroll
        for (int jj = 0; jj < 3; ++jj)
            acc[1+jj] = fmaf(node1[a*96 + c*3 + jj], u1, acc[1+jj]);
        #pragma unroll
        for (int ij = 0; ij < 9; ++ij)
            acc[4+ij] = fmaf(node2[a*288 + c*9 + ij], u2, acc[4+ij]);
    }
    #pragma unroll
    for (int sp = 0; sp < 13; ++sp)
        acc[sp] += __shfl_xor(acc[sp], 32);

    if (h == 0) {
        float* p = ws + NM_OFF + (size_t)a*512 + o*16;
        *(float4*)(p + 0)  = make_float4(acc[0], acc[1], acc[2], acc[3]);
        *(float4*)(p + 4)  = make_float4(acc[4], acc[5], acc[6], acc[7]);
        *(float4*)(p + 8)  = make_float4(acc[8], acc[9], acc[10], acc[11]);
        *(float4*)(p + 12) = make_float4(acc[12], 0.f, 0.f, 0.f);
    }
}

// Fused edge kernel, natural e-order (dense output writes), 8 threads/edge.
// Thread q accumulates s[w][4q..4q+3] in registers; per-edge g[96] shared via
// a per-GROUP LDS row. A group (tid>>3) is entirely within one wave64 and
// only touches its own row, and every thread's read range overlaps its own
// write range -> per-thread memory dependence orders ds_write before ds_read,
// and intra-wave LDS completes in order. NO __syncthreads needed: the
// block-wide barriers (and their forced vmcnt(0) drains, which serialized all
// outstanding L3 gathers 6x per block) were the round-3 stall.
__global__ __launch_bounds__(256) void edge_fused_k(
    const float* __restrict__ coord, const int* __restrict__ idx_i,
    const int* __restrict__ idx_j, const float* __restrict__ rbf_b,
    const float* __restrict__ V_w, const float* __restrict__ ws,
    float* __restrict__ out)
{
    __shared__ float gbuf[32 * 100];           // [group][96 + 4 pad]
    const int tid = threadIdx.x;
    const int grp = tid >> 3;
    const int q   = tid & 7;
    const int e   = blockIdx.x * 32 + grp;     // natural order
    const int i = idx_i[e];
    const int j = idx_j[e];

    float rx = coord[j*3+0] - coord[i*3+0];
    float ry = coord[j*3+1] - coord[i*3+1];
    float rz = coord[j*3+2] - coord[i*3+2];
    float d2 = rx*rx + ry*ry + rz*rz + 1e-12f;
    float dij = sqrtf(d2);
    float invd = 1.0f / dij;
    float ux = rx*invd, uy = ry*invd, uz = rz*invd;

    float tt = fminf(dij * 0.2f, 1.0f);
    float fc = 0.5f * (cosf(3.14159265358979323846f * tt) + 1.0f);
    float rbf[8];
    #pragma unroll
    for (int k = 0; k < 8; ++k) {
        float d = dij - (float)k * (5.0f / 7.0f);
        rbf[k] = expf(-4.0f * d * d) * fc;
    }

    const float* si = ws + SI_OFF;
    float sij = si[i*3+0]*si[j*3+0] + si[i*3+1]*si[j*3+1] + si[i*3+2]*si[j*3+2];
    float cheb1 = sij;
    float cheb2 = 2.0f * sij * sij - 1.0f;

    float sacc[3][4];
    #pragma unroll
    for (int w = 0; w < 3; ++w)
        #pragma unroll
        for (int r = 0; r < 4; ++r) sacc[w][r] = 0.0f;

    #pragma unroll
    for (int w = 0; w < 3; ++w) {
        const float* sbi = ws + SB_OFF + ((size_t)w*NA + i)*96 + q*12;
        const float* sbj = ws + SB_OFF + ((size_t)w*NA + j)*96 + q*12;
        const float* rwt = ws + RWT_OFF + w*768;   // [96][8]
        const float* rbb = rbf_b + w*96 + q*12;

        float4 bi0 = *(const float4*)(sbi + 0);
        float4 bi1 = *(const float4*)(sbi + 4);
        float4 bi2 = *(const float4*)(sbi + 8);
        float4 bj0 = *(const float4*)(sbj + 0);
        float4 bj1 = *(const float4*)(sbj + 4);
        float4 bj2 = *(const float4*)(sbj + 8);
        float4 rb0 = *(const float4*)(rbb + 0);
        float4 rb1 = *(const float4*)(rbb + 4);
        float4 rb2 = *(const float4*)(rbb + 8);
        float bi_[12] = {bi0.x,bi0.y,bi0.z,bi0.w, bi1.x,bi1.y,bi1.z,bi1.w,
                         bi2.x,bi2.y,bi2.z,bi2.w};
        float bj_[12] = {bj0.x,bj0.y,bj0.z,bj0.w, bj1.x,bj1.y,bj1.z,bj1.w,
                         bj2.x,bj2.y,bj2.z,bj2.w};
        float rb_[12] = {rb0.x,rb0.y,rb0.z,rb0.w, rb1.x,rb1.y,rb1.z,rb1.w,
                         rb2.x,rb2.y,rb2.z,rb2.w};

        float gv[12];
        #pragma unroll
        for (int kk = 0; kk < 12; ++kk) {
            int c = q*12 + kk;
            float4 ra = *(const float4*)(rwt + c*8);
            float4 rbx = *(const float4*)(rwt + c*8 + 4);
            float rm = rb_[kk];
            rm = fmaf(rbf[0], ra.x, rm);
            rm = fmaf(rbf[1], ra.y, rm);
            rm = fmaf(rbf[2], ra.z, rm);
            rm = fmaf(rbf[3], ra.w, rm);
            rm = fmaf(rbf[4], rbx.x, rm);
            rm = fmaf(rbf[5], rbx.y, rm);
            rm = fmaf(rbf[6], rbx.z, rm);
            rm = fmaf(rbf[7], rbx.w, rm);
            int tb = c >> 5;
            float chb = (tb == 0) ? 1.0f : ((tb == 1) ? cheb1 : cheb2);
            gv[kk] = rm * (bi_[kk] * bj_[kk]) * chb;
        }
        float* gb = gbuf + grp*100 + q*12;
        *(float4*)(gb + 0) = make_float4(gv[0], gv[1], gv[2],  gv[3]);
        *(float4*)(gb + 4) = make_float4(gv[4], gv[5], gv[6],  gv[7]);
        *(float4*)(gb + 8) = make_float4(gv[8], gv[9], gv[10], gv[11]);
        // no barrier: group == 8 lanes of one wave, own LDS row only;
        // per-thread write/read ranges alias -> hw in-order LDS suffices.

        const float* vw = V_w + w*3072 + q*4;      // [96][32], o-slice
        const float* gg = gbuf + grp*100;
        #pragma unroll 6
        for (int c4 = 0; c4 < 24; ++c4) {
            float4 g4 = *(const float4*)(gg + c4*4);
            float gcs[4] = {g4.x, g4.y, g4.z, g4.w};
            #pragma unroll
            for (int u4 = 0; u4 < 4; ++u4) {
                int c = c4*4 + u4;
                float gc = gcs[u4];
                float4 vv = *(const float4*)(vw + c*32);
                sacc[w][0] = fmaf(vv.x, gc, sacc[w][0]);
                sacc[w][1] = fmaf(vv.y, gc, sacc[w][1]);
                sacc[w][2] = fmaf(vv.z, gc, sacc[w][2]);
                sacc[w][3] = fmaf(vv.w, gc, sacc[w][3]);
            }
        }
    }

    // epilogue: thread q owns o = 4q..4q+3; s and u already in registers
    const float* nmj = ws + NM_OFF + (size_t)j*512 + q*64;

    float r0[4], r1[12], r2[36];
    #pragma unroll
    for (int oo = 0; oo < 4; ++oo) {
        const float* nmo = nmj + oo*16;
        float4 va  = *(const float4*)(nmo + 0);
        float4 vb  = *(const float4*)(nmo + 4);
        float4 vc4 = *(const float4*)(nmo + 8);
        float nd   = nmo[12];
        float n0 = va.x, n1x = va.y, n1y = va.z, n1z = va.w;
        float t00 = vb.x, t01 = vb.y, t02 = vb.z, t10 = vb.w;
        float t11 = vc4.x, t12 = vc4.y, t20 = vc4.z, t21 = vc4.w, t22 = nd;
        float s0 = sacc[0][oo], s1 = sacc[1][oo], s2 = sacc[2][oo];

        float d1 = n1x*ux + n1y*uy + n1z*uz;
        float m0 = t00*ux + t01*uy + t02*uz;
        float m1 = t10*ux + t11*uy + t12*uz;
        float m2 = t20*ux + t21*uy + t22*uz;
        float qq = m0*ux + m1*uy + m2*uz;

        r0[oo] = n0*s0 + d1*s1 + qq*s2;

        float w1 = n0*s1 + s2*d1;
        r1[oo*3+0] = w1*ux + n1x*s0 + s1*m0;
        r1[oo*3+1] = w1*uy + n1y*s0 + s1*m1;
        r1[oo*3+2] = w1*uz + n1z*s0 + s1*m2;

        float n0s2 = n0*s2;
        float a0 = ux*n0s2 + s1*n1x + s2*m0;
        float a1 = uy*n0s2 + s1*n1y + s2*m1;
        float a2 = uz*n0s2 + s1*n1z + s2*m2;
        r2[oo*9+0] = a0*ux + s0*t00;
        r2[oo*9+1] = a0*uy + s0*t01;
        r2[oo*9+2] = a0*uz + s0*t02;
        r2[oo*9+3] = a1*ux + s0*t10;
        r2[oo*9+4] = a1*uy + s0*t11;
        r2[oo*9+5] = a1*uz + s0*t12;
        r2[oo*9+6] = a2*ux + s0*t20;
        r2[oo*9+7] = a2*uy + s0*t21;
        r2[oo*9+8] = a2*uz + s0*t22;
    }

    *(float4*)(out + (size_t)e*32 + q*4) =
        make_float4(r0[0], r0[1], r0[2], r0[3]);

    float* p1 = out + (size_t)NE*32 + (size_t)e*96 + q*12;
    #pragma unroll
    for (int k = 0; k < 3; ++k)
        *(float4*)(p1 + k*4) =
            make_float4(r1[k*4+0], r1[k*4+1], r1[k*4+2], r1[k*4+3]);

    float* p2 = out + (size_t)NE*128 + (size_t)e*288 + q*36;
    #pragma unroll
    for (int k = 0; k < 9; ++k)
        *(float4*)(p2 + k*4) =
            make_float4(r2[k*4+0], r2[k*4+1], r2[k*4+2], r2[k*4+3]);
}

extern "C" void kernel_launch(void* const* d_in, const int* in_sizes, int n_in,
                              void* d_out, int out_size, void* d_ws, size_t ws_size,
                              hipStream_t stream) {
    const float* node0  = (const float*)d_in[0];
    const float* node1  = (const float*)d_in[1];
    const float* node2  = (const float*)d_in[2];
    const float* coord  = (const float*)d_in[3];
    const float* spin   = (const float*)d_in[4];
    const int*   idx_i  = (const int*)d_in[5];
    const int*   idx_j  = (const int*)d_in[6];
    const float* rbf_w  = (const float*)d_in[7];
    const float* rbf_b  = (const float*)d_in[8];
    const float* srbf_w = (const float*)d_in[9];
    const float* srbf_b = (const float*)d_in[10];
    const float* U_w    = (const float*)d_in[11];
    const float* V_w    = (const float*)d_in[12];
    float* out = (float*)d_out;
    float* ws  = (float*)d_ws;

    repack_rw_k<<<(2304 + 255) / 256, 256, 0, stream>>>(rbf_w, ws);
    atom_prep_k<<<NA / 4, 256, 0, stream>>>(node0, node1, node2, spin,
                                            srbf_w, srbf_b, U_w, ws);
    edge_fused_k<<<NE / 32, 256, 0, stream>>>(coord, idx_i, idx_j, rbf_b,
                                              V_w, ws, out);
}

// Round 5
// 785.630 us; speedup vs baseline: 1.0571x; 1.0525x over previous
//
#include <hip/hip_runtime.h>
#include <math.h>

#define NA 16384
#define NE 262144

// workspace layout in floats
#define SI_OFF   0                         // [NA][3]
#define SB_OFF   (NA*3)                    // [NA][3][96]  (interleaved by atom!)
#define NM_OFF   (SB_OFF + 3*NA*96)        // [NA][32][16]  (13 used, pad 16)
#define RWT_OFF  (NM_OFF + NA*512)         // [3][96][8]  rbf_w transposed
#define WS_FLOATS (RWT_OFF + 3*96*8)
// int region (reuse ws, cast to int*)
#define HIST_OFF (WS_FLOATS)               // [NA] ints
#define PERM_OFF (HIST_OFF + NA)           // [NE] ints

__global__ __launch_bounds__(256) void repack_rw_k(const float* __restrict__ rbf_w,
                                                   float* __restrict__ ws) {
    int t = blockIdx.x * 256 + threadIdx.x;       // over 3*96*8 = 2304
    if (t >= 2304) return;
    int k = t & 7;
    int c = (t >> 3) % 96;
    int w = t / 768;
    ws[RWT_OFF + t] = rbf_w[w * 768 + k * 96 + c];
}

__global__ __launch_bounds__(256) void hist_zero_k(int* __restrict__ hist) {
    int t = blockIdx.x * 256 + threadIdx.x;
    if (t < NA) hist[t] = 0;
}

__global__ __launch_bounds__(256) void hist_k(const int* __restrict__ idx_j,
                                              int* __restrict__ hist) {
    int e = blockIdx.x * 256 + threadIdx.x;
    if (e < NE) atomicAdd(&hist[idx_j[e]], 1);
}

// single block, 256 threads, 64 entries each: counts -> exclusive offsets
__global__ __launch_bounds__(256) void scan_k(int* __restrict__ hist) {
    __shared__ int sums[256];
    int t = threadIdx.x;
    int lo = t * 64;
    int s = 0;
    for (int k = 0; k < 64; ++k) s += hist[lo + k];
    sums[t] = s;
    __syncthreads();
    for (int off = 1; off < 256; off <<= 1) {
        int v = (t >= off) ? sums[t - off] : 0;
        __syncthreads();
        sums[t] += v;
        __syncthreads();
    }
    int ex = sums[t] - s;                 // exclusive prefix of this chunk
    for (int k = 0; k < 64; ++k) {
        int c = hist[lo + k];
        hist[lo + k] = ex;
        ex += c;
    }
}

__global__ __launch_bounds__(256) void scatter_k(const int* __restrict__ idx_j,
                                                 int* __restrict__ hist,
                                                 int* __restrict__ perm) {
    int e = blockIdx.x * 256 + threadIdx.x;
    if (e < NE) {
        int pos = atomicAdd(&hist[idx_j[e]], 1);
        perm[pos] = e;
    }
}

__global__ __launch_bounds__(256) void atom_prep_k(
    const float* __restrict__ node0, const float* __restrict__ node1,
    const float* __restrict__ node2, const float* __restrict__ spin,
    const float* __restrict__ srbf_w, const float* __restrict__ srbf_b,
    const float* __restrict__ U_w, float* __restrict__ ws)
{
    const int wave = threadIdx.x >> 6;
    const int lane = threadIdx.x & 63;
    const int a = blockIdx.x * 4 + wave;
    if (a >= NA) return;

    float sx = spin[a*3+0], sy = spin[a*3+1], sz = spin[a*3+2];
    float mi = sqrtf(sx*sx + sy*sy + sz*sz + 1e-12f);
    float inv = 1.0f / mi;
    if (lane < 3) ws[SI_OFF + a*3 + lane] = spin[a*3 + lane] * inv;

    float srbf[8];
    #pragma unroll
    for (int k = 0; k < 8; ++k) {
        float d = mi - (float)k * (3.0f / 7.0f);
        srbf[k] = expf(-4.0f * d * d);
    }

    // sb interleaved per atom: [a][w][c] -> one contiguous 1152B region/atom
    #pragma unroll
    for (int w = 0; w < 3; ++w) {
        #pragma unroll
        for (int rep = 0; rep < 2; ++rep) {
            int c = rep * 64 + lane;
            if (c < 96) {
                float acc = srbf_b[w*96 + c];
                #pragma unroll
                for (int k = 0; k < 8; ++k)
                    acc = fmaf(srbf[k], srbf_w[w*768 + k*96 + c], acc);
                ws[SB_OFF + (size_t)a*288 + w*96 + c] = acc;
            }
        }
    }

    const int o = lane & 31;
    const int h = lane >> 5;
    float acc[13];
    #pragma unroll
    for (int sp = 0; sp < 13; ++sp) acc[sp] = 0.0f;

    for (int cc = 0; cc < 16; ++cc) {
        int c = h * 16 + cc;
        float f0 = node0[a*32 + c];
        float u0 = U_w[0*1024 + c*32 + o];
        float u1 = U_w[1*1024 + c*32 + o];
        float u2 = U_w[2*1024 + c*32 + o];
        acc[0] = fmaf(f0, u0, acc[0]);
        #pragma unroll
        for (int jj = 0; jj < 3; ++jj)
            acc[1+jj] = fmaf(node1[a*96 + c*3 + jj], u1, acc[1+jj]);
        #pragma unroll
        for (int ij = 0; ij < 9; ++ij)
            acc[4+ij] = fmaf(node2[a*288 + c*9 + ij], u2, acc[4+ij]);
    }
    #pragma unroll
    for (int sp = 0; sp < 13; ++sp)
        acc[sp] += __shfl_xor(acc[sp], 32);

    if (h == 0) {
        float* p = ws + NM_OFF + (size_t)a*512 + o*16;
        *(float4*)(p + 0)  = make_float4(acc[0], acc[1], acc[2], acc[3]);
        *(float4*)(p + 4)  = make_float4(acc[4], acc[5], acc[6], acc[7]);
        *(float4*)(p + 8)  = make_float4(acc[8], acc[9], acc[10], acc[11]);
        *(float4*)(p + 12) = make_float4(acc[12], 0.f, 0.f, 0.f);
    }
}

// Fused edge kernel in PERM (j-sorted) order, 8 threads/edge.
// - sb_j and nm[j] are L1/L2-hot (consecutive groups share j; ~16 edges/atom)
// - sb_i is one contiguous 1152B burst per random i (interleaved layout)
// - no scratch round trip; s handed off in registers
// - output writes are scattered but full-line bursts (1+3+9 lines per edge)
// - no __syncthreads: each 8-thread group is inside one wave64 and only
//   touches its own LDS row; per-thread write/read ranges alias, so the
//   in-order DS pipe provides the ordering (validated rounds 3/4: same absmax)
// - launch_bounds(256,4): allow >64 VGPRs so the compiler can hoist the
//   independent sb_i/nm gathers (measured occupancy plateaus ~45% anyway)
__global__ __launch_bounds__(256, 4) void edge_fused_k(
    const float* __restrict__ coord, const int* __restrict__ idx_i,
    const int* __restrict__ idx_j, const float* __restrict__ rbf_b,
    const float* __restrict__ V_w, const float* __restrict__ ws,
    const int* __restrict__ perm, float* __restrict__ out)
{
    __shared__ float gbuf[32 * 100];           // [group][96 + 4 pad]
    const int tid = threadIdx.x;
    const int grp = tid >> 3;
    const int q   = tid & 7;
    const int g   = blockIdx.x * 32 + grp;     // sorted position
    const int e   = perm[g];
    const int i = idx_i[e];
    const int j = idx_j[e];

    float rx = coord[j*3+0] - coord[i*3+0];
    float ry = coord[j*3+1] - coord[i*3+1];
    float rz = coord[j*3+2] - coord[i*3+2];
    float d2 = rx*rx + ry*ry + rz*rz + 1e-12f;
    float dij = sqrtf(d2);
    float invd = 1.0f / dij;
    float ux = rx*invd, uy = ry*invd, uz = rz*invd;

    float tt = fminf(dij * 0.2f, 1.0f);
    float fc = 0.5f * (cosf(3.14159265358979323846f * tt) + 1.0f);
    float rbf[8];
    #pragma unroll
    for (int k = 0; k < 8; ++k) {
        float d = dij - (float)k * (5.0f / 7.0f);
        rbf[k] = expf(-4.0f * d * d) * fc;
    }

    const float* si = ws + SI_OFF;
    float sij = si[i*3+0]*si[j*3+0] + si[i*3+1]*si[j*3+1] + si[i*3+2]*si[j*3+2];
    float cheb1 = sij;
    float cheb2 = 2.0f * sij * sij - 1.0f;

    float sacc[3][4];
    #pragma unroll
    for (int w = 0; w < 3; ++w)
        #pragma unroll
        for (int r = 0; r < 4; ++r) sacc[w][r] = 0.0f;

    const float* sbi_base = ws + SB_OFF + (size_t)i*288 + q*12;
    const float* sbj_base = ws + SB_OFF + (size_t)j*288 + q*12;

    #pragma unroll
    for (int w = 0; w < 3; ++w) {
        const float* sbi = sbi_base + w*96;
        const float* sbj = sbj_base + w*96;
        const float* rwt = ws + RWT_OFF + w*768;   // [96][8]
        const float* rbb = rbf_b + w*96 + q*12;

        float4 bi0 = *(const float4*)(sbi + 0);
        float4 bi1 = *(const float4*)(sbi + 4);
        float4 bi2 = *(const float4*)(sbi + 8);
        float4 bj0 = *(const float4*)(sbj + 0);
        float4 bj1 = *(const float4*)(sbj + 4);
        float4 bj2 = *(const float4*)(sbj + 8);
        float4 rb0 = *(const float4*)(rbb + 0);
        float4 rb1 = *(const float4*)(rbb + 4);
        float4 rb2 = *(const float4*)(rbb + 8);
        float bi_[12] = {bi0.x,bi0.y,bi0.z,bi0.w, bi1.x,bi1.y,bi1.z,bi1.w,
                         bi2.x,bi2.y,bi2.z,bi2.w};
        float bj_[12] = {bj0.x,bj0.y,bj0.z,bj0.w, bj1.x,bj1.y,bj1.z,bj1.w,
                         bj2.x,bj2.y,bj2.z,bj2.w};
        float rb_[12] = {rb0.x,rb0.y,rb0.z,rb0.w, rb1.x,rb1.y,rb1.z,rb1.w,
                         rb2.x,rb2.y,rb2.z,rb2.w};

        float gv[12];
        #pragma unroll
        for (int kk = 0; kk < 12; ++kk) {
            int c = q*12 + kk;
            float4 ra = *(const float4*)(rwt + c*8);
            float4 rbx = *(const float4*)(rwt + c*8 + 4);
            float rm = rb_[kk];
            rm = fmaf(rbf[0], ra.x, rm);
            rm = fmaf(rbf[1], ra.y, rm);
            rm = fmaf(rbf[2], ra.z, rm);
            rm = fmaf(rbf[3], ra.w, rm);
            rm = fmaf(rbf[4], rbx.x, rm);
            rm = fmaf(rbf[5], rbx.y, rm);
            rm = fmaf(rbf[6], rbx.z, rm);
            rm = fmaf(rbf[7], rbx.w, rm);
            int tb = c >> 5;
            float chb = (tb == 0) ? 1.0f : ((tb == 1) ? cheb1 : cheb2);
            gv[kk] = rm * (bi_[kk] * bj_[kk]) * chb;
        }
        float* gb = gbuf + grp*100 + q*12;
        *(float4*)(gb + 0) = make_float4(gv[0], gv[1], gv[2],  gv[3]);
        *(float4*)(gb + 4) = make_float4(gv[4], gv[5], gv[6],  gv[7]);
        *(float4*)(gb + 8) = make_float4(gv[8], gv[9], gv[10], gv[11]);
        // no barrier: group == 8 lanes of one wave, own LDS row only.

        const float* vw = V_w + w*3072 + q*4;      // [96][32], o-slice
        const float* gg = gbuf + grp*100;
        #pragma unroll 6
        for (int c4 = 0; c4 < 24; ++c4) {
            float4 g4 = *(const float4*)(gg + c4*4);
            float gcs[4] = {g4.x, g4.y, g4.z, g4.w};
            #pragma unroll
            for (int u4 = 0; u4 < 4; ++u4) {
                int c = c4*4 + u4;
                float gc = gcs[u4];
                float4 vv = *(const float4*)(vw + c*32);
                sacc[w][0] = fmaf(vv.x, gc, sacc[w][0]);
                sacc[w][1] = fmaf(vv.y, gc, sacc[w][1]);
                sacc[w][2] = fmaf(vv.z, gc, sacc[w][2]);
                sacc[w][3] = fmaf(vv.w, gc, sacc[w][3]);
            }
        }
    }

    // epilogue: thread q owns o = 4q..4q+3; nm[j] is L1-hot in sorted order
    const float* nmj = ws + NM_OFF + (size_t)j*512 + q*64;

    float r0[4], r1[12], r2[36];
    #pragma unroll
    for (int oo = 0; oo < 4; ++oo) {
        const float* nmo = nmj + oo*16;
        float4 va  = *(const float4*)(nmo + 0);
        float4 vb  = *(const float4*)(nmo + 4);
        float4 vc4 = *(const float4*)(nmo + 8);
        float nd   = nmo[12];
        float n0 = va.x, n1x = va.y, n1y = va.z, n1z = va.w;
        float t00 = vb.x, t01 = vb.y, t02 = vb.z, t10 = vb.w;
        float t11 = vc4.x, t12 = vc4.y, t20 = vc4.z, t21 = vc4.w, t22 = nd;
        float s0 = sacc[0][oo], s1 = sacc[1][oo], s2 = sacc[2][oo];

        float d1 = n1x*ux + n1y*uy + n1z*uz;
        float m0 = t00*ux + t01*uy + t02*uz;
        float m1 = t10*ux + t11*uy + t12*uz;
        float m2 = t20*ux + t21*uy + t22*uz;
        float qq = m0*ux + m1*uy + m2*uz;

        r0[oo] = n0*s0 + d1*s1 + qq*s2;

        float w1 = n0*s1 + s2*d1;
        r1[oo*3+0] = w1*ux + n1x*s0 + s1*m0;
        r1[oo*3+1] = w1*uy + n1y*s0 + s1*m1;
        r1[oo*3+2] = w1*uz + n1z*s0 + s1*m2;

        float n0s2 = n0*s2;
        float a0 = ux*n0s2 + s1*n1x + s2*m0;
        float a1 = uy*n0s2 + s1*n1y + s2*m1;
        float a2 = uz*n0s2 + s1*n1z + s2*m2;
        r2[oo*9+0] = a0*ux + s0*t00;
        r2[oo*9+1] = a0*uy + s0*t01;
        r2[oo*9+2] = a0*uz + s0*t02;
        r2[oo*9+3] = a1*ux + s0*t10;
        r2[oo*9+4] = a1*uy + s0*t11;
        r2[oo*9+5] = a1*uz + s0*t12;
        r2[oo*9+6] = a2*ux + s0*t20;
        r2[oo*9+7] = a2*uy + s0*t21;
        r2[oo*9+8] = a2*uz + s0*t22;
    }

    // scattered but full-line output bursts: 9 + 3 + 1 lines per edge
    float* p2 = out + (size_t)NE*128 + (size_t)e*288 + q*36;
    #pragma unroll
    for (int k = 0; k < 9; ++k)
        *(float4*)(p2 + k*4) =
            make_float4(r2[k*4+0], r2[k*4+1], r2[k*4+2], r2[k*4+3]);

    float* p1 = out + (size_t)NE*32 + (size_t)e*96 + q*12;
    #pragma unroll
    for (int k = 0; k < 3; ++k)
        *(float4*)(p1 + k*4) =
            make_float4(r1[k*4+0], r1[k*4+1], r1[k*4+2], r1[k*4+3]);

    *(float4*)(out + (size_t)e*32 + q*4) =
        make_float4(r0[0], r0[1], r0[2], r0[3]);
}

extern "C" void kernel_launch(void* const* d_in, const int* in_sizes, int n_in,
                              void* d_out, int out_size, void* d_ws, size_t ws_size,
                              hipStream_t stream) {
    const float* node0  = (const float*)d_in[0];
    const float* node1  = (const float*)d_in[1];
    const float* node2  = (const float*)d_in[2];
    const float* coord  = (const float*)d_in[3];
    const float* spin   = (const float*)d_in[4];
    const int*   idx_i  = (const int*)d_in[5];
    const int*   idx_j  = (const int*)d_in[6];
    const float* rbf_w  = (const float*)d_in[7];
    const float* rbf_b  = (const float*)d_in[8];
    const float* srbf_w = (const float*)d_in[9];
    const float* srbf_b = (const float*)d_in[10];
    const float* U_w    = (const float*)d_in[11];
    const float* V_w    = (const float*)d_in[12];
    float* out = (float*)d_out;
    float* ws  = (float*)d_ws;
    int*   wsi = (int*)d_ws;
    int*   hist = wsi + HIST_OFF;
    int*   perm = wsi + PERM_OFF;

    repack_rw_k<<<(2304 + 255) / 256, 256, 0, stream>>>(rbf_w, ws);
    atom_prep_k<<<NA / 4, 256, 0, stream>>>(node0, node1, node2, spin,
                                            srbf_w, srbf_b, U_w, ws);
    hist_zero_k<<<NA / 256, 256, 0, stream>>>(hist);
    hist_k<<<NE / 256, 256, 0, stream>>>(idx_j, hist);
    scan_k<<<1, 256, 0, stream>>>(hist);
    scatter_k<<<NE / 256, 256, 0, stream>>>(idx_j, hist, perm);
    edge_fused_k<<<NE / 32, 256, 0, stream>>>(coord, idx_i, idx_j, rbf_b,
                                              V_w, ws, perm, out);
}

// Round 7
// 753.559 us; speedup vs baseline: 1.1021x; 1.0426x over previous
//
#include <hip/hip_runtime.h>
#include <math.h>

#define NA 16384
#define NE 262144

typedef float vfloat4 __attribute__((ext_vector_type(4)));

// workspace layout in floats
#define SI_OFF   0                         // [NA][3]
#define SB_OFF   (NA*3)                    // [3][NA][96]
#define NM_OFF   (SB_OFF + 3*NA*96)        // [NA][32][16]  (13 used, pad 16)
#define RWT_OFF  (NM_OFF + NA*512)         // [3][96][8]  rbf_w transposed
#define WS_FLOATS (RWT_OFF + 3*96*8)
// int region (reuse ws, cast to int*)
#define HIST_OFF (WS_FLOATS)               // [NA] ints
#define PERM_OFF (HIST_OFF + NA)           // [NE] ints

__global__ __launch_bounds__(256) void repack_rw_k(const float* __restrict__ rbf_w,
                                                   float* __restrict__ ws) {
    int t = blockIdx.x * 256 + threadIdx.x;       // over 3*96*8 = 2304
    if (t >= 2304) return;
    int k = t & 7;
    int c = (t >> 3) % 96;
    int w = t / 768;
    ws[RWT_OFF + t] = rbf_w[w * 768 + k * 96 + c];
}

__global__ __launch_bounds__(256) void hist_zero_k(int* __restrict__ hist) {
    int t = blockIdx.x * 256 + threadIdx.x;
    if (t < NA) hist[t] = 0;
}

__global__ __launch_bounds__(256) void hist_k(const int* __restrict__ idx_j,
                                              int* __restrict__ hist) {
    int e = blockIdx.x * 256 + threadIdx.x;
    if (e < NE) atomicAdd(&hist[idx_j[e]], 1);
}

// single block, 256 threads, 64 entries each: counts -> exclusive offsets
__global__ __launch_bounds__(256) void scan_k(int* __restrict__ hist) {
    __shared__ int sums[256];
    int t = threadIdx.x;
    int lo = t * 64;
    int s = 0;
    for (int k = 0; k < 64; ++k) s += hist[lo + k];
    sums[t] = s;
    __syncthreads();
    for (int off = 1; off < 256; off <<= 1) {
        int v = (t >= off) ? sums[t - off] : 0;
        __syncthreads();
        sums[t] += v;
        __syncthreads();
    }
    int ex = sums[t] - s;                 // exclusive prefix of this chunk
    for (int k = 0; k < 64; ++k) {
        int c = hist[lo + k];
        hist[lo + k] = ex;
        ex += c;
    }
}

__global__ __launch_bounds__(256) void scatter_k(const int* __restrict__ idx_j,
                                                 int* __restrict__ hist,
                                                 int* __restrict__ perm) {
    int e = blockIdx.x * 256 + threadIdx.x;
    if (e < NE) {
        int pos = atomicAdd(&hist[idx_j[e]], 1);
        perm[pos] = e;
    }
}

__global__ __launch_bounds__(256) void atom_prep_k(
    const float* __restrict__ node0, const float* __restrict__ node1,
    const float* __restrict__ node2, const float* __restrict__ spin,
    const float* __restrict__ srbf_w, const float* __restrict__ srbf_b,
    const float* __restrict__ U_w, float* __restrict__ ws)
{
    const int wave = threadIdx.x >> 6;
    const int lane = threadIdx.x & 63;
    const int a = blockIdx.x * 4 + wave;
    if (a >= NA) return;

    float sx = spin[a*3+0], sy = spin[a*3+1], sz = spin[a*3+2];
    float mi = sqrtf(sx*sx + sy*sy + sz*sz + 1e-12f);
    float inv = 1.0f / mi;
    if (lane < 3) ws[SI_OFF + a*3 + lane] = spin[a*3 + lane] * inv;

    float srbf[8];
    #pragma unroll
    for (int k = 0; k < 8; ++k) {
        float d = mi - (float)k * (3.0f / 7.0f);
        srbf[k] = expf(-4.0f * d * d);
    }

    #pragma unroll
    for (int w = 0; w < 3; ++w) {
        #pragma unroll
        for (int rep = 0; rep < 2; ++rep) {
            int c = rep * 64 + lane;
            if (c < 96) {
                float acc = srbf_b[w*96 + c];
                #pragma unroll
                for (int k = 0; k < 8; ++k)
                    acc = fmaf(srbf[k], srbf_w[w*768 + k*96 + c], acc);
                ws[SB_OFF + ((size_t)w*NA + a)*96 + c] = acc;
            }
        }
    }

    const int o = lane & 31;
    const int h = lane >> 5;
    float acc[13];
    #pragma unroll
    for (int sp = 0; sp < 13; ++sp) acc[sp] = 0.0f;

    for (int cc = 0; cc < 16; ++cc) {
        int c = h * 16 + cc;
        float f0 = node0[a*32 + c];
        float u0 = U_w[0*1024 + c*32 + o];
        float u1 = U_w[1*1024 + c*32 + o];
        float u2 = U_w[2*1024 + c*32 + o];
        acc[0] = fmaf(f0, u0, acc[0]);
        #pragma unroll
        for (int jj = 0; jj < 3; ++jj)
            acc[1+jj] = fmaf(node1[a*96 + c*3 + jj], u1, acc[1+jj]);
        #pragma unroll
        for (int ij = 0; ij < 9; ++ij)
            acc[4+ij] = fmaf(node2[a*288 + c*9 + ij], u2, acc[4+ij]);
    }
    #pragma unroll
    for (int sp = 0; sp < 13; ++sp)
        acc[sp] += __shfl_xor(acc[sp], 32);

    if (h == 0) {
        float* p = ws + NM_OFF + (size_t)a*512 + o*16;
        *(float4*)(p + 0)  = make_float4(acc[0], acc[1], acc[2], acc[3]);
        *(float4*)(p + 4)  = make_float4(acc[4], acc[5], acc[6], acc[7]);
        *(float4*)(p + 8)  = make_float4(acc[8], acc[9], acc[10], acc[11]);
        *(float4*)(p + 12) = make_float4(acc[12], 0.f, 0.f, 0.f);
    }
}

// Phase A (unchanged from round 2, measured ~190 us): per-edge s[3][32] + u,
// j-sorted (perm) order, w-sequential, writes 400B/edge into the edge's own
// z2 output slot (full 128B lines).
__global__ __launch_bounds__(256) void edge_s_k(
    const float* __restrict__ coord, const int* __restrict__ idx_i,
    const int* __restrict__ idx_j, const float* __restrict__ rbf_b,
    const float* __restrict__ V_w, const float* __restrict__ ws,
    const int* __restrict__ perm, float* __restrict__ out)
{
    const int t = blockIdx.x * 256 + threadIdx.x;
    const int e = perm[t];                 // edges sorted by idx_j for locality
    const int i = idx_i[e];
    const int j = idx_j[e];

    float rx = coord[j*3+0] - coord[i*3+0];
    float ry = coord[j*3+1] - coord[i*3+1];
    float rz = coord[j*3+2] - coord[i*3+2];
    float d2 = rx*rx + ry*ry + rz*rz + 1e-12f;
    float dij = sqrtf(d2);
    float invd = 1.0f / dij;
    float ux = rx*invd, uy = ry*invd, uz = rz*invd;

    float tt = fminf(dij * 0.2f, 1.0f);
    float fc = 0.5f * (cosf(3.14159265358979323846f * tt) + 1.0f);
    float rbf[8];
    #pragma unroll
    for (int k = 0; k < 8; ++k) {
        float d = dij - (float)k * (5.0f / 7.0f);
        rbf[k] = expf(-4.0f * d * d) * fc;
    }

    const float* si = ws + SI_OFF;
    float sij = si[i*3+0]*si[j*3+0] + si[i*3+1]*si[j*3+1] + si[i*3+2]*si[j*3+2];
    float cheb1 = sij;
    float cheb2 = 2.0f * sij * sij - 1.0f;

    float* o2 = out + (size_t)NE*128 + (size_t)e*288;

    #pragma unroll 1
    for (int w = 0; w < 3; ++w) {
        const float* sbi = ws + SB_OFF + ((size_t)w*NA + i)*96;
        const float* sbj = ws + SB_OFF + ((size_t)w*NA + j)*96;
        const float* rwt = ws + RWT_OFF + w*768;   // [96][8]
        const float* rbb = rbf_b + w*96;
        const float* vw  = V_w + w*3072;           // [96][32]

        float s[32];
        #pragma unroll
        for (int o = 0; o < 32; ++o) s[o] = 0.0f;

        #pragma unroll
        for (int tb = 0; tb < 3; ++tb) {
            float chb = (tb == 0) ? 1.0f : ((tb == 1) ? cheb1 : cheb2);
            #pragma unroll 4
            for (int cc = 0; cc < 8; ++cc) {
                int c0 = tb*32 + cc*4;
                float4 vi = *(const float4*)(sbi + c0);
                float4 vj = *(const float4*)(sbj + c0);
                float pv[4];
                pv[0] = vi.x * vj.x; pv[1] = vi.y * vj.y;
                pv[2] = vi.z * vj.z; pv[3] = vi.w * vj.w;
                #pragma unroll
                for (int q = 0; q < 4; ++q) {
                    int c = c0 + q;
                    float rm = rbb[c];
                    #pragma unroll
                    for (int k = 0; k < 8; ++k)
                        rm = fmaf(rbf[k], rwt[c*8 + k], rm);
                    float g = rm * pv[q] * chb;
                    const float* vc = vw + c*32;
                    #pragma unroll
                    for (int o = 0; o < 32; ++o)
                        s[o] = fmaf(vc[o], g, s[o]);
                }
            }
        }

        // one full 128B line per way
        #pragma unroll
        for (int og = 0; og < 8; ++og)
            *(float4*)(o2 + w*32 + og*4) =
                make_float4(s[og*4+0], s[og*4+1], s[og*4+2], s[og*4+3]);
    }

    // 4th line: u vector + zero padding (full 128B line, no RFO)
    *(float4*)(o2 + 96)  = make_float4(ux, uy, uz, 0.0f);
    #pragma unroll
    for (int k = 1; k < 8; ++k)
        *(float4*)(o2 + 96 + k*4) = make_float4(0.f, 0.f, 0.f, 0.f);
}

// Phase B: NATURAL e-order (dense full-line output writes), 8 threads/edge.
// All 20 float4 loads (4 scratch + 16 nm) issued into register arrays BEFORE
// any compute -> 20 outstanding gathers/thread; launch_bounds(256,2) lifts
// the 64-VGPR cap that serialized loads in rounds 1/2. Nontemporal output
// stores (never re-read) keep L2 capacity for the nm gather; nontemporal
// scratch loads (read-once stream) likewise. vfloat4 (clang ext_vector_type)
// is required by __builtin_nontemporal_*; layout-identical to float4.
__global__ __launch_bounds__(256, 2) void edge_out_k(
    const int* __restrict__ idx_j, const float* __restrict__ ws,
    float* __restrict__ out)
{
    const int t = blockIdx.x * 256 + threadIdx.x;  // 8*NE threads
    const int e = t >> 3;
    const int q = t & 7;
    const int j = idx_j[e];

    float* o2base = out + (size_t)NE*128 + (size_t)e*288;

    // ---- issue all loads first ----
    vfloat4 v0 = __builtin_nontemporal_load((const vfloat4*)(o2base + q*4));
    vfloat4 v1 = __builtin_nontemporal_load((const vfloat4*)(o2base + 32 + q*4));
    vfloat4 v2 = __builtin_nontemporal_load((const vfloat4*)(o2base + 64 + q*4));
    vfloat4 uu = __builtin_nontemporal_load((const vfloat4*)(o2base + 96));
    const float* nmj = ws + NM_OFF + (size_t)j*512 + q*64;
    vfloat4 nm[16];
    #pragma unroll
    for (int k = 0; k < 16; ++k)
        nm[k] = *(const vfloat4*)(nmj + k*4);

    float ux = uu.x, uy = uu.y, uz = uu.z;
    float c0[4] = {v0.x, v0.y, v0.z, v0.w};
    float c1[4] = {v1.x, v1.y, v1.z, v1.w};
    float c2[4] = {v2.x, v2.y, v2.z, v2.w};

    float r0[4], r1[12], r2[36];
    #pragma unroll
    for (int oo = 0; oo < 4; ++oo) {
        vfloat4 va  = nm[oo*4+0];
        vfloat4 vb  = nm[oo*4+1];
        vfloat4 vc4 = nm[oo*4+2];
        float nd    = nm[oo*4+3].x;
        float n0 = va.x, n1x = va.y, n1y = va.z, n1z = va.w;
        float t00 = vb.x, t01 = vb.y, t02 = vb.z, t10 = vb.w;
        float t11 = vc4.x, t12 = vc4.y, t20 = vc4.z, t21 = vc4.w, t22 = nd;
        float s0 = c0[oo], s1 = c1[oo], s2 = c2[oo];

        float d1 = n1x*ux + n1y*uy + n1z*uz;
        float m0 = t00*ux + t01*uy + t02*uz;
        float m1 = t10*ux + t11*uy + t12*uz;
        float m2 = t20*ux + t21*uy + t22*uz;
        float qq = m0*ux + m1*uy + m2*uz;

        r0[oo] = n0*s0 + d1*s1 + qq*s2;

        float w1 = n0*s1 + s2*d1;
        r1[oo*3+0] = w1*ux + n1x*s0 + s1*m0;
        r1[oo*3+1] = w1*uy + n1y*s0 + s1*m1;
        r1[oo*3+2] = w1*uz + n1z*s0 + s1*m2;

        float n0s2 = n0*s2;
        float a0 = ux*n0s2 + s1*n1x + s2*m0;
        float a1 = uy*n0s2 + s1*n1y + s2*m1;
        float a2 = uz*n0s2 + s1*n1z + s2*m2;
        r2[oo*9+0] = a0*ux + s0*t00;
        r2[oo*9+1] = a0*uy + s0*t01;
        r2[oo*9+2] = a0*uz + s0*t02;
        r2[oo*9+3] = a1*ux + s0*t10;
        r2[oo*9+4] = a1*uy + s0*t11;
        r2[oo*9+5] = a1*uz + s0*t12;
        r2[oo*9+6] = a2*ux + s0*t20;
        r2[oo*9+7] = a2*uy + s0*t21;
        r2[oo*9+8] = a2*uz + s0*t22;
    }

    vfloat4 w0; w0.x = r0[0]; w0.y = r0[1]; w0.z = r0[2]; w0.w = r0[3];
    __builtin_nontemporal_store(w0, (vfloat4*)(out + (size_t)e*32 + q*4));

    float* p1 = out + (size_t)NE*32 + (size_t)e*96 + q*12;
    #pragma unroll
    for (int k = 0; k < 3; ++k) {
        vfloat4 wv; wv.x = r1[k*4+0]; wv.y = r1[k*4+1];
        wv.z = r1[k*4+2]; wv.w = r1[k*4+3];
        __builtin_nontemporal_store(wv, (vfloat4*)(p1 + k*4));
    }

    float* p2 = o2base + q*36;
    #pragma unroll
    for (int k = 0; k < 9; ++k) {
        vfloat4 wv; wv.x = r2[k*4+0]; wv.y = r2[k*4+1];
        wv.z = r2[k*4+2]; wv.w = r2[k*4+3];
        __builtin_nontemporal_store(wv, (vfloat4*)(p2 + k*4));
    }
}

extern "C" void kernel_launch(void* const* d_in, const int* in_sizes, int n_in,
                              void* d_out, int out_size, void* d_ws, size_t ws_size,
                              hipStream_t stream) {
    const float* node0  = (const float*)d_in[0];
    const float* node1  = (const float*)d_in[1];
    const float* node2  = (const float*)d_in[2];
    const float* coord  = (const float*)d_in[3];
    const float* spin   = (const float*)d_in[4];
    const int*   idx_i  = (const int*)d_in[5];
    const int*   idx_j  = (const int*)d_in[6];
    const float* rbf_w  = (const float*)d_in[7];
    const float* rbf_b  = (const float*)d_in[8];
    const float* srbf_w = (const float*)d_in[9];
    const float* srbf_b = (const float*)d_in[10];
    const float* U_w    = (const float*)d_in[11];
    const float* V_w    = (const float*)d_in[12];
    float* out = (float*)d_out;
    float* ws  = (float*)d_ws;
    int*   wsi = (int*)d_ws;
    int*   hist = wsi + HIST_OFF;
    int*   perm = wsi + PERM_OFF;

    repack_rw_k<<<(2304 + 255) / 256, 256, 0, stream>>>(rbf_w, ws);
    atom_prep_k<<<NA / 4, 256, 0, stream>>>(node0, node1, node2, spin,
                                            srbf_w, srbf_b, U_w, ws);
    hist_zero_k<<<NA / 256, 256, 0, stream>>>(hist);
    hist_k<<<NE / 256, 256, 0, stream>>>(idx_j, hist);
    scan_k<<<1, 256, 0, stream>>>(hist);
    scatter_k<<<NE / 256, 256, 0, stream>>>(idx_j, hist, perm);
    edge_s_k<<<NE / 256, 256, 0, stream>>>(coord, idx_i, idx_j, rbf_b,
                                           V_w, ws, perm, out);
    edge_out_k<<<(NE * 8) / 256, 256, 0, stream>>>(idx_j, ws, out);
}

// Round 8
// 496.322 us; speedup vs baseline: 1.6733x; 1.5183x over previous
//
#include <hip/hip_runtime.h>
#include <math.h>

#define NA 16384
#define NE 262144

// workspace layout in floats
#define SI_OFF   0                         // [NA][3]
#define SB_OFF   (NA*3)                    // [3][NA][96]
#define NM_OFF   (SB_OFF + 3*NA*96)        // [NA][32][16]  (13 used, pad 16)
#define RWT_OFF  (NM_OFF + NA*512)         // [3][96][8]  rbf_w transposed
#define WS_FLOATS (RWT_OFF + 3*96*8)
// int region (reuse ws, cast to int*)
#define HIST_OFF (WS_FLOATS)               // [NA] ints
#define PERM_OFF (HIST_OFF + NA)           // [NE] ints

__global__ __launch_bounds__(256) void repack_rw_k(const float* __restrict__ rbf_w,
                                                   float* __restrict__ ws) {
    int t = blockIdx.x * 256 + threadIdx.x;       // over 3*96*8 = 2304
    if (t >= 2304) return;
    int k = t & 7;
    int c = (t >> 3) % 96;
    int w = t / 768;
    ws[RWT_OFF + t] = rbf_w[w * 768 + k * 96 + c];
}

__global__ __launch_bounds__(256) void hist_zero_k(int* __restrict__ hist) {
    int t = blockIdx.x * 256 + threadIdx.x;
    if (t < NA) hist[t] = 0;
}

__global__ __launch_bounds__(256) void hist_k(const int* __restrict__ idx_j,
                                              int* __restrict__ hist) {
    int e = blockIdx.x * 256 + threadIdx.x;
    if (e < NE) atomicAdd(&hist[idx_j[e]], 1);
}

// single block, 256 threads, 64 entries each: counts -> exclusive offsets
__global__ __launch_bounds__(256) void scan_k(int* __restrict__ hist) {
    __shared__ int sums[256];
    int t = threadIdx.x;
    int lo = t * 64;
    int s = 0;
    for (int k = 0; k < 64; ++k) s += hist[lo + k];
    sums[t] = s;
    __syncthreads();
    for (int off = 1; off < 256; off <<= 1) {
        int v = (t >= off) ? sums[t - off] : 0;
        __syncthreads();
        sums[t] += v;
        __syncthreads();
    }
    int ex = sums[t] - s;                 // exclusive prefix of this chunk
    for (int k = 0; k < 64; ++k) {
        int c = hist[lo + k];
        hist[lo + k] = ex;
        ex += c;
    }
}

__global__ __launch_bounds__(256) void scatter_k(const int* __restrict__ idx_j,
                                                 int* __restrict__ hist,
                                                 int* __restrict__ perm) {
    int e = blockIdx.x * 256 + threadIdx.x;
    if (e < NE) {
        int pos = atomicAdd(&hist[idx_j[e]], 1);
        perm[pos] = e;
    }
}

__global__ __launch_bounds__(256) void atom_prep_k(
    const float* __restrict__ node0, const float* __restrict__ node1,
    const float* __restrict__ node2, const float* __restrict__ spin,
    const float* __restrict__ srbf_w, const float* __restrict__ srbf_b,
    const float* __restrict__ U_w, float* __restrict__ ws)
{
    const int wave = threadIdx.x >> 6;
    const int lane = threadIdx.x & 63;
    const int a = blockIdx.x * 4 + wave;
    if (a >= NA) return;

    float sx = spin[a*3+0], sy = spin[a*3+1], sz = spin[a*3+2];
    float mi = sqrtf(sx*sx + sy*sy + sz*sz + 1e-12f);
    float inv = 1.0f / mi;
    if (lane < 3) ws[SI_OFF + a*3 + lane] = spin[a*3 + lane] * inv;

    float srbf[8];
    #pragma unroll
    for (int k = 0; k < 8; ++k) {
        float d = mi - (float)k * (3.0f / 7.0f);
        srbf[k] = expf(-4.0f * d * d);
    }

    #pragma unroll
    for (int w = 0; w < 3; ++w) {
        #pragma unroll
        for (int rep = 0; rep < 2; ++rep) {
            int c = rep * 64 + lane;
            if (c < 96) {
                float acc = srbf_b[w*96 + c];
                #pragma unroll
                for (int k = 0; k < 8; ++k)
                    acc = fmaf(srbf[k], srbf_w[w*768 + k*96 + c], acc);
                ws[SB_OFF + ((size_t)w*NA + a)*96 + c] = acc;
            }
        }
    }

    const int o = lane & 31;
    const int h = lane >> 5;
    float acc[13];
    #pragma unroll
    for (int sp = 0; sp < 13; ++sp) acc[sp] = 0.0f;

    for (int cc = 0; cc < 16; ++cc) {
        int c = h * 16 + cc;
        float f0 = node0[a*32 + c];
        float u0 = U_w[0*1024 + c*32 + o];
        float u1 = U_w[1*1024 + c*32 + o];
        float u2 = U_w[2*1024 + c*32 + o];
        acc[0] = fmaf(f0, u0, acc[0]);
        #pragma unroll
        for (int jj = 0; jj < 3; ++jj)
            acc[1+jj] = fmaf(node1[a*96 + c*3 + jj], u1, acc[1+jj]);
        #pragma unroll
        for (int ij = 0; ij < 9; ++ij)
            acc[4+ij] = fmaf(node2[a*288 + c*9 + ij], u2, acc[4+ij]);
    }
    #pragma unroll
    for (int sp = 0; sp < 13; ++sp)
        acc[sp] += __shfl_xor(acc[sp], 32);

    if (h == 0) {
        float* p = ws + NM_OFF + (size_t)a*512 + o*16;
        *(float4*)(p + 0)  = make_float4(acc[0], acc[1], acc[2], acc[3]);
        *(float4*)(p + 4)  = make_float4(acc[4], acc[5], acc[6], acc[7]);
        *(float4*)(p + 8)  = make_float4(acc[8], acc[9], acc[10], acc[11]);
        *(float4*)(p + 12) = make_float4(acc[12], 0.f, 0.f, 0.f);
    }
}

// Phase A (unchanged from round 2): per-edge s[3][32] + u, j-sorted (perm)
// order, w-sequential, writes 400B/edge into the edge's own z2 output slot.
__global__ __launch_bounds__(256) void edge_s_k(
    const float* __restrict__ coord, const int* __restrict__ idx_i,
    const int* __restrict__ idx_j, const float* __restrict__ rbf_b,
    const float* __restrict__ V_w, const float* __restrict__ ws,
    const int* __restrict__ perm, float* __restrict__ out)
{
    const int t = blockIdx.x * 256 + threadIdx.x;
    const int e = perm[t];                 // edges sorted by idx_j for locality
    const int i = idx_i[e];
    const int j = idx_j[e];

    float rx = coord[j*3+0] - coord[i*3+0];
    float ry = coord[j*3+1] - coord[i*3+1];
    float rz = coord[j*3+2] - coord[i*3+2];
    float d2 = rx*rx + ry*ry + rz*rz + 1e-12f;
    float dij = sqrtf(d2);
    float invd = 1.0f / dij;
    float ux = rx*invd, uy = ry*invd, uz = rz*invd;

    float tt = fminf(dij * 0.2f, 1.0f);
    float fc = 0.5f * (cosf(3.14159265358979323846f * tt) + 1.0f);
    float rbf[8];
    #pragma unroll
    for (int k = 0; k < 8; ++k) {
        float d = dij - (float)k * (5.0f / 7.0f);
        rbf[k] = expf(-4.0f * d * d) * fc;
    }

    const float* si = ws + SI_OFF;
    float sij = si[i*3+0]*si[j*3+0] + si[i*3+1]*si[j*3+1] + si[i*3+2]*si[j*3+2];
    float cheb1 = sij;
    float cheb2 = 2.0f * sij * sij - 1.0f;

    float* o2 = out + (size_t)NE*128 + (size_t)e*288;

    #pragma unroll 1
    for (int w = 0; w < 3; ++w) {
        const float* sbi = ws + SB_OFF + ((size_t)w*NA + i)*96;
        const float* sbj = ws + SB_OFF + ((size_t)w*NA + j)*96;
        const float* rwt = ws + RWT_OFF + w*768;   // [96][8]
        const float* rbb = rbf_b + w*96;
        const float* vw  = V_w + w*3072;           // [96][32]

        float s[32];
        #pragma unroll
        for (int o = 0; o < 32; ++o) s[o] = 0.0f;

        #pragma unroll
        for (int tb = 0; tb < 3; ++tb) {
            float chb = (tb == 0) ? 1.0f : ((tb == 1) ? cheb1 : cheb2);
            #pragma unroll 4
            for (int cc = 0; cc < 8; ++cc) {
                int c0 = tb*32 + cc*4;
                float4 vi = *(const float4*)(sbi + c0);
                float4 vj = *(const float4*)(sbj + c0);
                float pv[4];
                pv[0] = vi.x * vj.x; pv[1] = vi.y * vj.y;
                pv[2] = vi.z * vj.z; pv[3] = vi.w * vj.w;
                #pragma unroll
                for (int q = 0; q < 4; ++q) {
                    int c = c0 + q;
                    float rm = rbb[c];
                    #pragma unroll
                    for (int k = 0; k < 8; ++k)
                        rm = fmaf(rbf[k], rwt[c*8 + k], rm);
                    float g = rm * pv[q] * chb;
                    const float* vc = vw + c*32;
                    #pragma unroll
                    for (int o = 0; o < 32; ++o)
                        s[o] = fmaf(vc[o], g, s[o]);
                }
            }
        }

        // one full 128B line per way
        #pragma unroll
        for (int og = 0; og < 8; ++og)
            *(float4*)(o2 + w*32 + og*4) =
                make_float4(s[og*4+0], s[og*4+1], s[og*4+2], s[og*4+3]);
    }

    // 4th line: u vector + zero padding (full 128B line, no RFO)
    *(float4*)(o2 + 96)  = make_float4(ux, uy, uz, 0.0f);
    #pragma unroll
    for (int k = 1; k < 8; ++k)
        *(float4*)(o2 + 96 + k*4) = make_float4(0.f, 0.f, 0.f, 0.f);
}

__device__ __forceinline__ void edge_epilogue(
    int e, int q,
    float4 v0, float4 v1, float4 v2, float4 uu,
    const float4* nmv, const float* nd4, float* __restrict__ out)
{
    float ux = uu.x, uy = uu.y, uz = uu.z;
    float c0[4] = {v0.x, v0.y, v0.z, v0.w};
    float c1[4] = {v1.x, v1.y, v1.z, v1.w};
    float c2[4] = {v2.x, v2.y, v2.z, v2.w};

    float r0[4], r1[12], r2[36];
    #pragma unroll
    for (int oo = 0; oo < 4; ++oo) {
        float4 va  = nmv[oo*3+0];
        float4 vb  = nmv[oo*3+1];
        float4 vc4 = nmv[oo*3+2];
        float nd   = nd4[oo];
        float n0 = va.x, n1x = va.y, n1y = va.z, n1z = va.w;
        float t00 = vb.x, t01 = vb.y, t02 = vb.z, t10 = vb.w;
        float t11 = vc4.x, t12 = vc4.y, t20 = vc4.z, t21 = vc4.w, t22 = nd;
        float s0 = c0[oo], s1 = c1[oo], s2 = c2[oo];

        float d1 = n1x*ux + n1y*uy + n1z*uz;
        float m0 = t00*ux + t01*uy + t02*uz;
        float m1 = t10*ux + t11*uy + t12*uz;
        float m2 = t20*ux + t21*uy + t22*uz;
        float qq = m0*ux + m1*uy + m2*uz;

        r0[oo] = n0*s0 + d1*s1 + qq*s2;

        float w1 = n0*s1 + s2*d1;
        r1[oo*3+0] = w1*ux + n1x*s0 + s1*m0;
        r1[oo*3+1] = w1*uy + n1y*s0 + s1*m1;
        r1[oo*3+2] = w1*uz + n1z*s0 + s1*m2;

        float n0s2 = n0*s2;
        float a0 = ux*n0s2 + s1*n1x + s2*m0;
        float a1 = uy*n0s2 + s1*n1y + s2*m1;
        float a2 = uz*n0s2 + s1*n1z + s2*m2;
        r2[oo*9+0] = a0*ux + s0*t00;
        r2[oo*9+1] = a0*uy + s0*t01;
        r2[oo*9+2] = a0*uz + s0*t02;
        r2[oo*9+3] = a1*ux + s0*t10;
        r2[oo*9+4] = a1*uy + s0*t11;
        r2[oo*9+5] = a1*uz + s0*t12;
        r2[oo*9+6] = a2*ux + s0*t20;
        r2[oo*9+7] = a2*uy + s0*t21;
        r2[oo*9+8] = a2*uz + s0*t22;
    }

    *(float4*)(out + (size_t)e*32 + q*4) =
        make_float4(r0[0], r0[1], r0[2], r0[3]);

    float* p1 = out + (size_t)NE*32 + (size_t)e*96 + q*12;
    #pragma unroll
    for (int k = 0; k < 3; ++k)
        *(float4*)(p1 + k*4) =
            make_float4(r1[k*4+0], r1[k*4+1], r1[k*4+2], r1[k*4+3]);

    float* p2 = out + (size_t)NE*128 + (size_t)e*288 + q*36;
    #pragma unroll
    for (int k = 0; k < 9; ++k)
        *(float4*)(p2 + k*4) =
            make_float4(r2[k*4+0], r2[k*4+1], r2[k*4+2], r2[k*4+3]);
}

// Phase B: NATURAL order (dense writes), 8 threads/edge, 2-deep software
// pipeline: each group owns edges g and g+NE/2 (both halves write-dense).
// ALL loads for both edges are issued up front and pinned by
// sched_barrier(0); edge-b's gather latency hides under edge-a's
// compute+stores. launch_bounds(256,2) budgets ~200 VGPR for the in-flight
// values. Plain stores (nt stores caused 2.5x write amplification, r7).
__global__ __launch_bounds__(256, 2) void edge_out_k(
    const int* __restrict__ idx_j, const float* __restrict__ ws,
    float* __restrict__ out)
{
    const int t = blockIdx.x * 256 + threadIdx.x;  // (NE/2)*8 threads
    const int g = t >> 3;
    const int q = t & 7;
    const int ea = g;
    const int eb = g + NE/2;
    const int ja = idx_j[ea];
    const int jb = idx_j[eb];

    const float* o2a = out + (size_t)NE*128 + (size_t)ea*288;
    const float* o2b = out + (size_t)NE*128 + (size_t)eb*288;
    const float* nma = ws + NM_OFF + (size_t)ja*512 + q*64;
    const float* nmb = ws + NM_OFF + (size_t)jb*512 + q*64;

    // ---- issue ALL loads for BOTH edges ----
    float4 a_v0 = *(const float4*)(o2a + q*4);
    float4 a_v1 = *(const float4*)(o2a + 32 + q*4);
    float4 a_v2 = *(const float4*)(o2a + 64 + q*4);
    float4 a_uu = *(const float4*)(o2a + 96);
    float4 a_nm[12];
    float  a_nd[4];
    #pragma unroll
    for (int oo = 0; oo < 4; ++oo) {
        a_nm[oo*3+0] = *(const float4*)(nma + oo*16 + 0);
        a_nm[oo*3+1] = *(const float4*)(nma + oo*16 + 4);
        a_nm[oo*3+2] = *(const float4*)(nma + oo*16 + 8);
        a_nd[oo]     = nma[oo*16 + 12];
    }
    float4 b_v0 = *(const float4*)(o2b + q*4);
    float4 b_v1 = *(const float4*)(o2b + 32 + q*4);
    float4 b_v2 = *(const float4*)(o2b + 64 + q*4);
    float4 b_uu = *(const float4*)(o2b + 96);
    float4 b_nm[12];
    float  b_nd[4];
    #pragma unroll
    for (int oo = 0; oo < 4; ++oo) {
        b_nm[oo*3+0] = *(const float4*)(nmb + oo*16 + 0);
        b_nm[oo*3+1] = *(const float4*)(nmb + oo*16 + 4);
        b_nm[oo*3+2] = *(const float4*)(nmb + oo*16 + 8);
        b_nd[oo]     = nmb[oo*16 + 12];
    }
    // pin the schedule: nothing below may be hoisted above, nothing above
    // may be sunk below -> all 32 gathers stay in flight together
    __builtin_amdgcn_sched_barrier(0);

    edge_epilogue(ea, q, a_v0, a_v1, a_v2, a_uu, a_nm, a_nd, out);
    edge_epilogue(eb, q, b_v0, b_v1, b_v2, b_uu, b_nm, b_nd, out);
}

extern "C" void kernel_launch(void* const* d_in, const int* in_sizes, int n_in,
                              void* d_out, int out_size, void* d_ws, size_t ws_size,
                              hipStream_t stream) {
    const float* node0  = (const float*)d_in[0];
    const float* node1  = (const float*)d_in[1];
    const float* node2  = (const float*)d_in[2];
    const float* coord  = (const float*)d_in[3];
    const float* spin   = (const float*)d_in[4];
    const int*   idx_i  = (const int*)d_in[5];
    const int*   idx_j  = (const int*)d_in[6];
    const float* rbf_w  = (const float*)d_in[7];
    const float* rbf_b  = (const float*)d_in[8];
    const float* srbf_w = (const float*)d_in[9];
    const float* srbf_b = (const float*)d_in[10];
    const float* U_w    = (const float*)d_in[11];
    const float* V_w    = (const float*)d_in[12];
    float* out = (float*)d_out;
    float* ws  = (float*)d_ws;
    int*   wsi = (int*)d_ws;
    int*   hist = wsi + HIST_OFF;
    int*   perm = wsi + PERM_OFF;

    repack_rw_k<<<(2304 + 255) / 256, 256, 0, stream>>>(rbf_w, ws);
    atom_prep_k<<<NA / 4, 256, 0, stream>>>(node0, node1, node2, spin,
                                            srbf_w, srbf_b, U_w, ws);
    hist_zero_k<<<NA / 256, 256, 0, stream>>>(hist);
    hist_k<<<NE / 256, 256, 0, stream>>>(idx_j, hist);
    scan_k<<<1, 256, 0, stream>>>(hist);
    scatter_k<<<NE / 256, 256, 0, stream>>>(idx_j, hist, perm);
    edge_s_k<<<NE / 256, 256, 0, stream>>>(coord, idx_i, idx_j, rbf_b,
                                           V_w, ws, perm, out);
    edge_out_k<<<(NE / 2 * 8) / 256, 256, 0, stream>>>(idx_j, ws, out);
}